// Round 1
// baseline (102.107 us; speedup 1.0000x reference)
//
#include <hip/hip_runtime.h>

// Problem constants (match reference)
#define BB 2
#define NN 131072
#define MM 512
#define GG 20
#define VV (GG * GG * GG)   // 8000

// ---- order-preserving float<->uint encoding for atomicMin on floats ----
__device__ __forceinline__ unsigned f_enc(float f) {
    unsigned u = __float_as_uint(f);
    return (u & 0x80000000u) ? ~u : (u | 0x80000000u);
}
__device__ __forceinline__ float f_dec(unsigned u) {
    return __uint_as_float((u & 0x80000000u) ? (u & 0x7FFFFFFFu) : ~u);
}

// ---- Kernel 1: per-batch coordinate min --------------------------------
// x viewed as (B, N, 3). Per batch: 393216 floats = 98304 float4 = 32768
// groups of 3 float4 (= 4 points). Full-BW vectorized read.
__global__ void vox_min_kernel(const float* __restrict__ x,
                               unsigned* __restrict__ minEnc) {
    const int b = blockIdx.y;
    const float4* xb = (const float4*)(x + (size_t)b * NN * 3);
    const int ngroups = (NN * 3) / 12;  // 32768

    float mx = 1e30f, my = 1e30f, mz = 1e30f;
    for (int g = blockIdx.x * blockDim.x + threadIdx.x; g < ngroups;
         g += gridDim.x * blockDim.x) {
        float4 f0 = xb[3 * g + 0];
        float4 f1 = xb[3 * g + 1];
        float4 f2 = xb[3 * g + 2];
        // points: (f0.x f0.y f0.z) (f0.w f1.x f1.y) (f1.z f1.w f2.x) (f2.y f2.z f2.w)
        mx = fminf(mx, fminf(fminf(f0.x, f0.w), fminf(f1.z, f2.y)));
        my = fminf(my, fminf(fminf(f0.y, f1.x), fminf(f1.w, f2.z)));
        mz = fminf(mz, fminf(fminf(f0.z, f1.y), fminf(f2.x, f2.w)));
    }
    // wave-64 shuffle reduction
    for (int off = 32; off > 0; off >>= 1) {
        mx = fminf(mx, __shfl_down(mx, off, 64));
        my = fminf(my, __shfl_down(my, off, 64));
        mz = fminf(mz, __shfl_down(mz, off, 64));
    }
    if ((threadIdx.x & 63) == 0) {
        atomicMin(&minEnc[b * 3 + 0], f_enc(mx));
        atomicMin(&minEnc[b * 3 + 1], f_enc(my));
        atomicMin(&minEnc[b * 3 + 2], f_enc(mz));
    }
}

__device__ __forceinline__ int vox_coord(float p, float mn) {
    int i = (int)floorf((p - mn) * 2.0f);  // * 2 == / 0.5, exact pow2 scale
    return min(max(i, 0), GG - 1);
}

// ---- Kernel 2: mark needed voxels + record sampled flat ids ------------
__global__ void vox_mark_kernel(const float* __restrict__ x,
                                const int* __restrict__ sidx,
                                const unsigned* __restrict__ minEnc,
                                int* __restrict__ sflat,
                                int* __restrict__ flags) {
    int t = blockIdx.x * blockDim.x + threadIdx.x;
    if (t >= BB * MM) return;
    int b = t / MM;
    int pi = sidx[t];
    const float* p = x + ((size_t)b * NN + pi) * 3;
    float mnx = f_dec(minEnc[b * 3 + 0]);
    float mny = f_dec(minEnc[b * 3 + 1]);
    float mnz = f_dec(minEnc[b * 3 + 2]);
    int ix = vox_coord(p[0], mnx);
    int iy = vox_coord(p[1], mny);
    int iz = vox_coord(p[2], mnz);
    int flat = (ix * GG + iy) * GG + iz;
    sflat[t] = flat;
    flags[b * VV + flat] = 1;
}

// ---- Kernel 3: accumulate sums only for flagged voxels -----------------
// sums layout per (b,voxel): [cnt, sx, sy, sz, sxx, sxy, sxz, syy, syz, szz]
__global__ void vox_accum_kernel(const float* __restrict__ x,
                                 const unsigned* __restrict__ minEnc,
                                 const int* __restrict__ flags,
                                 float* __restrict__ sums) {
    const int b = blockIdx.y;
    const float mnx = f_dec(minEnc[b * 3 + 0]);
    const float mny = f_dec(minEnc[b * 3 + 1]);
    const float mnz = f_dec(minEnc[b * 3 + 2]);
    const float* xb = x + (size_t)b * NN * 3;

    for (int i = blockIdx.x * blockDim.x + threadIdx.x; i < NN;
         i += gridDim.x * blockDim.x) {
        float px = xb[3 * i + 0];
        float py = xb[3 * i + 1];
        float pz = xb[3 * i + 2];
        int ix = vox_coord(px, mnx);
        int iy = vox_coord(py, mny);
        int iz = vox_coord(pz, mnz);
        int flat = (ix * GG + iy) * GG + iz;
        if (flags[b * VV + flat]) {
            float* s = sums + (size_t)(b * VV + flat) * 10;
            atomicAdd(s + 0, 1.0f);
            atomicAdd(s + 1, px);
            atomicAdd(s + 2, py);
            atomicAdd(s + 3, pz);
            atomicAdd(s + 4, px * px);
            atomicAdd(s + 5, px * py);
            atomicAdd(s + 6, px * pz);
            atomicAdd(s + 7, py * py);
            atomicAdd(s + 8, py * pz);
            atomicAdd(s + 9, pz * pz);
        }
    }
}

// ---- Kernel 4: finalize mean/cov at sampled voxels ---------------------
__global__ void vox_final_kernel(const float* __restrict__ sums,
                                 const int* __restrict__ sflat,
                                 float* __restrict__ out) {
    int t = blockIdx.x * blockDim.x + threadIdx.x;
    if (t >= BB * MM) return;
    int b = t / MM;
    int flat = sflat[t];
    const float* s = sums + (size_t)(b * VV + flat) * 10;
    float cnt = s[0];
    float safe = fmaxf(cnt, 1.0f);
    float inv = 1.0f / safe;
    float mx = s[1] * inv, my = s[2] * inv, mz = s[3] * inv;
    float cxx = s[4] * inv - mx * mx;
    float cxy = s[5] * inv - mx * my;
    float cxz = s[6] * inv - mx * mz;
    float cyy = s[7] * inv - my * my;
    float cyz = s[8] * inv - my * mz;
    float czz = s[9] * inv - mz * mz;
    float* o = out + (size_t)t * 12;
    o[0] = mx;  o[1] = my;  o[2] = mz;
    o[3] = cxx; o[4] = cxy; o[5] = cxz;
    o[6] = cxy; o[7] = cyy; o[8] = cyz;
    o[9] = cxz; o[10] = cyz; o[11] = czz;
}

extern "C" void kernel_launch(void* const* d_in, const int* in_sizes, int n_in,
                              void* d_out, int out_size, void* d_ws, size_t ws_size,
                              hipStream_t stream) {
    const float* x = (const float*)d_in[0];       // (B, N, 3) fp32
    const int* sidx = (const int*)d_in[1];        // (B, M) int32
    float* out = (float*)d_out;                   // (B, M, 12) fp32

    char* ws = (char*)d_ws;
    // workspace layout (≈714 KB total):
    //   [0, 24)          minEnc  : B*3 uint   (init 0xFF = +inf encoded)
    //   [256, 4352)      sflat   : B*M int
    //   [8192, 72192)    flags   : B*V int    (init 0)
    //   [73728, 713728)  sums    : B*V*10 f32 (init 0)
    unsigned* minEnc = (unsigned*)ws;
    int* sflat = (int*)(ws + 256);
    int* flags = (int*)(ws + 8192);
    float* sums = (float*)(ws + 8192 + 65536);

    hipMemsetAsync(minEnc, 0xFF, BB * 3 * sizeof(unsigned), stream);
    hipMemsetAsync(ws + 8192, 0, 65536 + (size_t)BB * VV * 10 * sizeof(float),
                   stream);

    vox_min_kernel<<<dim3(64, BB), 256, 0, stream>>>(x, minEnc);
    vox_mark_kernel<<<(BB * MM + 255) / 256, 256, 0, stream>>>(x, sidx, minEnc,
                                                               sflat, flags);
    vox_accum_kernel<<<dim3(256, BB), 256, 0, stream>>>(x, minEnc, flags, sums);
    vox_final_kernel<<<(BB * MM + 255) / 256, 256, 0, stream>>>(sums, sflat, out);
}